// Round 1
// baseline (446.239 us; speedup 1.0000x reference)
//
#include <hip/hip_runtime.h>
#include <math.h>

#define H 128
#define NF 100000
#define NC 25000
#define TR 64          // rows per block tile

__device__ __forceinline__ float silu_f(float v) {
    return v / (1.0f + __expf(-v));
}

// Accumulate acc[4][8] += A_T[k][4*rg..] * W[k][8*cg..] over k=0..127.
// sSrc: transposed activation tile [128][TR] in LDS.
// Wp:   weight block [128][H] row-major in global (L2-resident).
__device__ __forceinline__ void gemm_acc(const float* __restrict__ sSrc,
                                         const float* __restrict__ Wp,
                                         int cg, int rg, float acc[4][8])
{
    #pragma unroll 4
    for (int k = 0; k < H; ++k) {
        float4 a  = *(const float4*)(sSrc + k * TR + 4 * rg);
        float4 w0 = *(const float4*)(Wp + (size_t)k * H + 8 * cg);
        float4 w1 = *(const float4*)(Wp + (size_t)k * H + 8 * cg + 4);
        float av[4] = {a.x, a.y, a.z, a.w};
        float wv[8] = {w0.x, w0.y, w0.z, w0.w, w1.x, w1.y, w1.z, w1.w};
        #pragma unroll
        for (int rr = 0; rr < 4; ++rr)
            #pragma unroll
            for (int i = 0; i < 8; ++i)
                acc[rr][i] = fmaf(av[rr], wv[i], acc[rr][i]);
    }
}

// Stage one row (128 f32) transposed into LDS tile [128][TR].
// r = row slot (0..63), q = k-quarter (0..3): this thread covers k = 32q..32q+31.
__device__ __forceinline__ void stage_T(const float* __restrict__ src,
                                        float* __restrict__ dst, int r, int q)
{
    #pragma unroll
    for (int kk = 0; kk < 8; ++kk) {
        int k = q * 32 + kk * 4;
        float4 v = *(const float4*)(src + k);
        dst[(k + 0) * TR + r] = v.x;
        dst[(k + 1) * TR + r] = v.y;
        dst[(k + 2) * TR + r] = v.z;
        dst[(k + 3) * TR + r] = v.w;
    }
}

__global__ __launch_bounds__(256, 2)
void fused_mlp_f32(const float* __restrict__ x,     // [2][25000][128]
                   const float* __restrict__ xs,    // [2][100000][128]
                   const int*   __restrict__ f2c,   // [100000]
                   const float* __restrict__ dist,  // [100000]
                   const float* __restrict__ W1,    // [257][128]
                   const float* __restrict__ b1,    // [128]
                   const float* __restrict__ W2,    // [128][128]
                   const float* __restrict__ b2,
                   const float* __restrict__ W3,    // [128][128]
                   const float* __restrict__ b3,
                   float* __restrict__ out)         // [200000][128]
{
    __shared__ float sA[H * TR];   // 32 KB: layer input, transposed [k][row]
    __shared__ float sHt[H * TR];  // 32 KB: hidden, transposed
    __shared__ float sD[TR];

    const int t  = threadIdx.x;
    const int cg = t & 15;   // col group: cols 8*cg .. 8*cg+7
    const int rg = t >> 4;   // row group: rows 4*rg .. 4*rg+3 (0..15)
    const int r  = t & 63;   // staging row slot
    const int q  = t >> 6;   // staging k-quarter

    const long long R0 = (long long)blockIdx.x * TR;

    // row -> (b, n) for this thread's staging row
    const long long Rs = R0 + r;
    const int bb = (Rs >= NF) ? 1 : 0;
    const int nn = (int)(Rs - (long long)bb * NF);

    // ---- stage gathered coarse rows (transposed) + distances ----
    {
        const int ci = f2c[nn];
        const float* src = x + ((long long)bb * NC + ci) * H;
        stage_T(src, sA, r, q);
        if (t < TR) sD[t] = dist[nn];
    }
    __syncthreads();

    // ---- layer 1: acc = b1 + d*W1[256] + xg@W1[0:128] + xs@W1[128:256] ----
    float acc[4][8];
    {
        float4 bb0 = *(const float4*)(b1 + 8 * cg);
        float4 bb1 = *(const float4*)(b1 + 8 * cg + 4);
        float4 wc0 = *(const float4*)(W1 + 256 * H + 8 * cg);
        float4 wc1 = *(const float4*)(W1 + 256 * H + 8 * cg + 4);
        #pragma unroll
        for (int rr = 0; rr < 4; ++rr) {
            float dv = sD[4 * rg + rr];
            acc[rr][0] = bb0.x + dv * wc0.x;
            acc[rr][1] = bb0.y + dv * wc0.y;
            acc[rr][2] = bb0.z + dv * wc0.z;
            acc[rr][3] = bb0.w + dv * wc0.w;
            acc[rr][4] = bb1.x + dv * wc1.x;
            acc[rr][5] = bb1.y + dv * wc1.y;
            acc[rr][6] = bb1.z + dv * wc1.z;
            acc[rr][7] = bb1.w + dv * wc1.w;
        }
    }

    gemm_acc(sA, W1, cg, rg, acc);              // xg part (W1 rows 0..127)
    __syncthreads();                             // all waves done reading sA

    // restage sA with x_scale rows (transposed)
    {
        const float* src = xs + ((long long)bb * NF + nn) * H;
        stage_T(src, sA, r, q);
    }
    __syncthreads();

    gemm_acc(sA, W1 + 128 * H, cg, rg, acc);    // xs part (W1 rows 128..255)

    // silu -> sHt (transposed)
    #pragma unroll
    for (int rr = 0; rr < 4; ++rr)
        #pragma unroll
        for (int i = 0; i < 8; ++i)
            sHt[(8 * cg + i) * TR + 4 * rg + rr] = silu_f(acc[rr][i]);
    __syncthreads();

    // ---- layer 2 ----
    {
        float4 bb0 = *(const float4*)(b2 + 8 * cg);
        float4 bb1 = *(const float4*)(b2 + 8 * cg + 4);
        #pragma unroll
        for (int rr = 0; rr < 4; ++rr) {
            acc[rr][0] = bb0.x; acc[rr][1] = bb0.y; acc[rr][2] = bb0.z; acc[rr][3] = bb0.w;
            acc[rr][4] = bb1.x; acc[rr][5] = bb1.y; acc[rr][6] = bb1.z; acc[rr][7] = bb1.w;
        }
    }
    gemm_acc(sHt, W2, cg, rg, acc);
    __syncthreads();                             // done reading sA from L1? (sA free) / keep order

    // silu -> sA (reuse, transposed)
    #pragma unroll
    for (int rr = 0; rr < 4; ++rr)
        #pragma unroll
        for (int i = 0; i < 8; ++i)
            sA[(8 * cg + i) * TR + 4 * rg + rr] = silu_f(acc[rr][i]);
    __syncthreads();

    // ---- layer 3 ----
    {
        float4 bb0 = *(const float4*)(b3 + 8 * cg);
        float4 bb1 = *(const float4*)(b3 + 8 * cg + 4);
        #pragma unroll
        for (int rr = 0; rr < 4; ++rr) {
            acc[rr][0] = bb0.x; acc[rr][1] = bb0.y; acc[rr][2] = bb0.z; acc[rr][3] = bb0.w;
            acc[rr][4] = bb1.x; acc[rr][5] = bb1.y; acc[rr][6] = bb1.z; acc[rr][7] = bb1.w;
        }
    }
    gemm_acc(sA, W3, cg, rg, acc);

    // ---- store out [R][128] ----
    #pragma unroll
    for (int rr = 0; rr < 4; ++rr) {
        long long R = R0 + 4 * rg + rr;
        float4 o0 = make_float4(acc[rr][0], acc[rr][1], acc[rr][2], acc[rr][3]);
        float4 o1 = make_float4(acc[rr][4], acc[rr][5], acc[rr][6], acc[rr][7]);
        *(float4*)(out + R * H + 8 * cg)     = o0;
        *(float4*)(out + R * H + 8 * cg + 4) = o1;
    }
}

extern "C" void kernel_launch(void* const* d_in, const int* in_sizes, int n_in,
                              void* d_out, int out_size, void* d_ws, size_t ws_size,
                              hipStream_t stream)
{
    const float* x    = (const float*)d_in[0];
    const float* xs   = (const float*)d_in[1];
    const int*   f2c  = (const int*)d_in[2];
    const float* dist = (const float*)d_in[3];
    const float* W1   = (const float*)d_in[4];
    const float* b1   = (const float*)d_in[5];
    const float* W2   = (const float*)d_in[6];
    const float* b2   = (const float*)d_in[7];
    const float* W3   = (const float*)d_in[8];
    const float* b3   = (const float*)d_in[9];
    float* out = (float*)d_out;

    const int n_rows = 2 * NF;                  // 200000
    dim3 grid((n_rows + TR - 1) / TR);          // 3125
    fused_mlp_f32<<<grid, 256, 0, stream>>>(x, xs, f2c, dist,
                                            W1, b1, W2, b2, W3, b3, out);
}

// Round 4
// 242.006 us; speedup vs baseline: 1.8439x; 1.8439x over previous
//
#include <hip/hip_runtime.h>
#include <math.h>

#define H 128
#define NF 100000
#define NC 25000
#define TM 64

typedef __bf16 bf16;
typedef bf16 bf16x8 __attribute__((ext_vector_type(8)));
typedef bf16 bf16x4 __attribute__((ext_vector_type(4)));
typedef float f32x4 __attribute__((ext_vector_type(4)));

#define MFMA(a, b, c) __builtin_amdgcn_mfma_f32_16x16x32_bf16((a), (b), (c), 0, 0, 0)

// ws layout in bf16 elements:
//   0      WT1hi [128][256]   (W1^T, k<256; row 256 of W1 handled as rank-1)
//   32768  WT1lo
//   65536  WT2hi [128][128]
//   81920  WT2lo
//   98304  WT3hi
//   114688 WT3lo
// total 131072 bf16 = 256 KiB

__global__ void prep_w(const float* __restrict__ W1, const float* __restrict__ W2,
                       const float* __restrict__ W3, bf16* __restrict__ ws)
{
    int i = blockIdx.x * 256 + threadIdx.x;   // 0..65535, grid exact
    float v; bf16* hp; bf16* lp; int idx;
    if (i < 32768) {                          // W1^T: n = i>>8, k = i&255
        int n = i >> 8, k = i & 255;
        v = W1[k * H + n]; hp = ws; lp = ws + 32768; idx = i;
    } else if (i < 49152) {                   // W2^T
        int j = i - 32768, n = j >> 7, k = j & 127;
        v = W2[k * H + n]; hp = ws + 65536; lp = ws + 81920; idx = j;
    } else {                                  // W3^T
        int j = i - 49152, n = j >> 7, k = j & 127;
        v = W3[k * H + n]; hp = ws + 98304; lp = ws + 114688; idx = j;
    }
    bf16 h = (bf16)v;
    hp[idx] = h;
    lp[idx] = (bf16)(v - (float)h);
}

__device__ __forceinline__ float silu_f(float v) {
    return v / (1.0f + __expf(-v));
}

// element index into a [TM][H] bf16 plane with 16B-slot XOR swizzle
__device__ __forceinline__ int swz(int row, int col) {
    return row * H + (((col >> 3) ^ (row & 7)) << 3) + (col & 7);
}

// A-fragment read: lane l, M-tile base row mrow, k-step base k (=kk*32)
__device__ __forceinline__ bf16x8 ldsA(const bf16* __restrict__ p, int row, int k) {
    int idx = row * H + ((((k >> 3) ^ (row & 7))) << 3);   // k already lane-offset, mult of 8
    return *(const bf16x8*)(p + idx);
}

// One K=128 GEMM chunk: acc[mt][nt] += A(rows wRow+mt*16..) * W^T(cols wCol+nt*16..)
// 3-product split accumulation.
__device__ __forceinline__ void gemm3(const bf16* __restrict__ Ah, const bf16* __restrict__ Al,
                                      const bf16* __restrict__ Bh, const bf16* __restrict__ Bl,
                                      int Ks, int kbase, int wRow, int wCol, int l,
                                      f32x4 acc[2][4])
{
    const int lr = l & 15, lg = l >> 4;
    #pragma unroll
    for (int kk = 0; kk < 4; ++kk) {
        const int k = kk * 32 + (lg << 3);
        bf16x8 a0h = ldsA(Ah, wRow + lr, k);
        bf16x8 a0l = ldsA(Al, wRow + lr, k);
        bf16x8 a1h = ldsA(Ah, wRow + 16 + lr, k);
        bf16x8 a1l = ldsA(Al, wRow + 16 + lr, k);
        #pragma unroll
        for (int nt = 0; nt < 4; ++nt) {
            long off = (long)(wCol + nt * 16 + lr) * Ks + kbase + k;
            bf16x8 bh = *(const bf16x8*)(Bh + off);
            bf16x8 bl = *(const bf16x8*)(Bl + off);
            acc[0][nt] = MFMA(a0h, bh, acc[0][nt]);
            acc[0][nt] = MFMA(a0l, bh, acc[0][nt]);
            acc[0][nt] = MFMA(a0h, bl, acc[0][nt]);
            acc[1][nt] = MFMA(a1h, bh, acc[1][nt]);
            acc[1][nt] = MFMA(a1l, bh, acc[1][nt]);
            acc[1][nt] = MFMA(a1h, bl, acc[1][nt]);
        }
    }
}

// silu + split + swizzled store of a wave's 32x64 result into LDS planes
__device__ __forceinline__ void store_h(const f32x4 acc[2][4], bf16* __restrict__ Dh,
                                        bf16* __restrict__ Dl, int wRow, int wCol, int l)
{
    const int lr = l & 15, lg = l >> 4;
    #pragma unroll
    for (int mt = 0; mt < 2; ++mt)
        #pragma unroll
        for (int nt = 0; nt < 4; ++nt)
            #pragma unroll
            for (int r = 0; r < 4; ++r) {
                int row = wRow + mt * 16 + lg * 4 + r;
                int col = wCol + nt * 16 + lr;
                float v = silu_f(acc[mt][nt][r]);
                bf16 h = (bf16)v;
                int idx = swz(row, col);
                Dh[idx] = h;
                Dl[idx] = (bf16)(v - (float)h);
            }
}

__global__ __launch_bounds__(256, 2)
void fused_mlp_mfma(const float* __restrict__ x,     // [2][25000][128]
                    const float* __restrict__ xsc,   // [2][100000][128]
                    const int*   __restrict__ f2c,   // [100000]
                    const float* __restrict__ dist,  // [100000]
                    const float* __restrict__ W1,    // [257][128] (row 256 used)
                    const float* __restrict__ b1,
                    const float* __restrict__ b2,
                    const float* __restrict__ b3,
                    const bf16*  __restrict__ ws,    // prepped weights
                    float* __restrict__ out)         // [200000][128]
{
    __shared__ __align__(16) bf16 s0h[TM * H], s0l[TM * H];
    __shared__ __align__(16) bf16 s1h[TM * H], s1l[TM * H];
    __shared__ float sD[TM];
    __shared__ int   sCI[TM];

    const int t = threadIdx.x;
    const int l = t & 63, w = t >> 6;
    const int wRow = (w >> 1) * 32;      // 0 or 32
    const int wCol = (w & 1) * 64;       // 0 or 64
    const long long R0 = (long long)blockIdx.x * TM;

    // ---- per-row metadata ----
    if (t < TM) {
        long long Rs = R0 + t;
        int bb = Rs >= NF;
        int nn = (int)(Rs - (long long)bb * NF);
        sCI[t] = f2c[nn];
        sD[t]  = dist[nn];
    }
    __syncthreads();

    // ---- stage xg -> s0, xs -> s1 (f32 -> bf16 hi/lo, swizzled) ----
    #pragma unroll
    for (int i = 0; i < 8; ++i) {
        int f = i * 256 + t;              // float4 index within tile (0..2047)
        int row = f >> 5;
        int k0  = (f & 31) * 4;
        long long Rs = R0 + row;
        int bb = Rs >= NF;

        // x_scale: linear rows
        float4 v = *(const float4*)(xsc + Rs * H + k0);
        bf16x4 hi, lo;
        float a0 = v.x, a1 = v.y, a2 = v.z, a3 = v.w;
        hi[0] = (bf16)a0; hi[1] = (bf16)a1; hi[2] = (bf16)a2; hi[3] = (bf16)a3;
        lo[0] = (bf16)(a0 - (float)hi[0]); lo[1] = (bf16)(a1 - (float)hi[1]);
        lo[2] = (bf16)(a2 - (float)hi[2]); lo[3] = (bf16)(a3 - (float)hi[3]);
        int idx = swz(row, k0);
        *(bf16x4*)(s1h + idx) = hi;
        *(bf16x4*)(s1l + idx) = lo;

        // gathered coarse rows
        const float* src = x + ((long long)bb * NC + sCI[row]) * H + k0;
        float4 g = *(const float4*)src;
        a0 = g.x; a1 = g.y; a2 = g.z; a3 = g.w;
        hi[0] = (bf16)a0; hi[1] = (bf16)a1; hi[2] = (bf16)a2; hi[3] = (bf16)a3;
        lo[0] = (bf16)(a0 - (float)hi[0]); lo[1] = (bf16)(a1 - (float)hi[1]);
        lo[2] = (bf16)(a2 - (float)hi[2]); lo[3] = (bf16)(a3 - (float)hi[3]);
        *(bf16x4*)(s0h + idx) = hi;
        *(bf16x4*)(s0l + idx) = lo;
    }
    __syncthreads();

    const bf16* WT1h = ws;
    const bf16* WT1l = ws + 32768;
    const bf16* WT2h = ws + 65536;
    const bf16* WT2l = ws + 81920;
    const bf16* WT3h = ws + 98304;
    const bf16* WT3l = ws + 114688;

    const int lr = l & 15, lg = l >> 4;

    // ---- layer 1: acc = b1 + d*W1[256] + xg@W1[0:128] + xs@W1[128:256] ----
    f32x4 acc[2][4];
    #pragma unroll
    for (int nt = 0; nt < 4; ++nt) {
        int col = wCol + nt * 16 + lr;
        float bc = b1[col];
        float wc = W1[256 * H + col];
        #pragma unroll
        for (int mt = 0; mt < 2; ++mt)
            #pragma unroll
            for (int r = 0; r < 4; ++r)
                acc[mt][nt][r] = bc + sD[wRow + mt * 16 + lg * 4 + r] * wc;
    }
    gemm3(s0h, s0l, WT1h, WT1l, 256, 0,   wRow, wCol, l, acc);
    gemm3(s1h, s1l, WT1h, WT1l, 256, 128, wRow, wCol, l, acc);
    __syncthreads();                       // everyone done reading s0/s1

    store_h(acc, s0h, s0l, wRow, wCol, l); // h1 -> s0 (overwrites xg)
    __syncthreads();

    // ---- layer 2 ----
    #pragma unroll
    for (int nt = 0; nt < 4; ++nt) {
        float bc = b2[wCol + nt * 16 + lr];
        #pragma unroll
        for (int mt = 0; mt < 2; ++mt)
            #pragma unroll
            for (int r = 0; r < 4; ++r)
                acc[mt][nt][r] = bc;
    }
    gemm3(s0h, s0l, WT2h, WT2l, 128, 0, wRow, wCol, l, acc);
    __syncthreads();                       // done reading s0 (h1)

    store_h(acc, s1h, s1l, wRow, wCol, l); // h2 -> s1
    __syncthreads();

    // ---- layer 3 ----
    #pragma unroll
    for (int nt = 0; nt < 4; ++nt) {
        float bc = b3[wCol + nt * 16 + lr];
        #pragma unroll
        for (int mt = 0; mt < 2; ++mt)
            #pragma unroll
            for (int r = 0; r < 4; ++r)
                acc[mt][nt][r] = bc;
    }
    gemm3(s1h, s1l, WT3h, WT3l, 128, 0, wRow, wCol, l, acc);

    // ---- store out ----
    #pragma unroll
    for (int mt = 0; mt < 2; ++mt)
        #pragma unroll
        for (int nt = 0; nt < 4; ++nt)
            #pragma unroll
            for (int r = 0; r < 4; ++r) {
                long long row = R0 + wRow + mt * 16 + lg * 4 + r;
                int col = wCol + nt * 16 + lr;
                out[row * H + col] = acc[mt][nt][r];
            }
}

extern "C" void kernel_launch(void* const* d_in, const int* in_sizes, int n_in,
                              void* d_out, int out_size, void* d_ws, size_t ws_size,
                              hipStream_t stream)
{
    const float* x    = (const float*)d_in[0];
    const float* xsc  = (const float*)d_in[1];
    const int*   f2c  = (const int*)d_in[2];
    const float* dist = (const float*)d_in[3];
    const float* W1   = (const float*)d_in[4];
    const float* b1   = (const float*)d_in[5];
    const float* W2   = (const float*)d_in[6];
    const float* b2   = (const float*)d_in[7];
    const float* W3   = (const float*)d_in[8];
    const float* b3   = (const float*)d_in[9];
    bf16* ws = (bf16*)d_ws;

    prep_w<<<256, 256, 0, stream>>>(W1, W2, W3, ws);

    const int n_rows = 2 * NF;                    // 200000
    dim3 grid(n_rows / TM);                       // 3125
    fused_mlp_mfma<<<grid, 256, 0, stream>>>(x, xsc, f2c, dist, W1, b1, b2, b3,
                                             ws, (float*)d_out);
}